// Round 4
// baseline (662.370 us; speedup 1.0000x reference)
//
#include <hip/hip_runtime.h>
#include <math.h>

#define Bn 4096
#define Tn 512
#define Vn 57
#define En 20
#define Hn 128
#define On 18
#define ROWS 16          // batch rows per block (= MFMA N, fully used)
#define NTHR 128         // 2 waves, one per SIMD: minimal barrier domain
#define NBLK (Bn / ROWS) // 256 blocks -> 1 per CU (LDS pad keeps it that way)
#define KC 5             // A K-chunks: 4x32 (W_hh) + 1x32 (W_ih 20 + bias 1 + 11 zero)
#define ESTR 66          // embT row stride (halfs): word bank = (id+4q)%32, id-gather clean
#define XSTR 513         // staged x row stride (ints): bank=(r+t)%32, conflict-free
#define HFSTR 132        // final-h fp32 row stride
#define ASCALE 2.8853900817779268f   // 2*log2(e): folds tanh's 2x and log2e mul into A

typedef _Float16 half8  __attribute__((ext_vector_type(8)));
typedef __fp16   fp16x2 __attribute__((ext_vector_type(2)));   // cvt_pkrtz native type
typedef float    floatx4 __attribute__((ext_vector_type(4)));

// acc is pre-scaled by 2*log2e: tanh(x) = 1 - 2/(1+2^(2x*log2e))
__device__ __forceinline__ float tanh_scaled(float z) {
    float e = __builtin_amdgcn_exp2f(z);          // v_exp_f32
    float r = __builtin_amdgcn_rcpf(e + 1.0f);    // v_rcp_f32
    return fmaf(-2.0f, r, 1.0f);
}

__device__ __forceinline__ unsigned pk_u32(fp16x2 v) {
    union { fp16x2 h; unsigned u; } c; c.h = v; return c.u;
}

__device__ __forceinline__ half8 as_half8(uint4 v) {
    union { uint4 u; half8 h; } c; c.u = v; return c.h;
}

// (128, 1): 2 waves/block, 1 block/CU -> 1 wave/SIMD, VGPR cap 512; demand ~160.
__launch_bounds__(NTHR, 1)
__global__ void rnn_mfma_kernel(const int* __restrict__ x,
                                const int* __restrict__ xlen,
                                const float* __restrict__ emb,
                                const float* __restrict__ W_ih,
                                const float* __restrict__ W_hh,
                                const float* __restrict__ b_ih,
                                const float* __restrict__ b_hh,
                                const float* __restrict__ W_out,
                                const float* __restrict__ b_out,
                                float* __restrict__ out)
{
    // Exchange: h-fragment kc for lane l at exB[buf][kc][l] (uint4 = half8,
    // k = 32kc+8q+j, batch col n = l&15). Wave u OWNS frags 2u,2u+1 in registers
    // (C->B in-place via the per-tile A-row permutation); only the OTHER wave's
    // 2 frags cross LDS. Double-buffered: ONE 2-wave barrier per step.
    __shared__ __align__(16) uint4    exB[2][4][64];
    __shared__ __align__(16) _Float16 sEmb[Vn * ESTR];  // cols 0..19 emb, 20 = 1.0, 21..31 = 0
    __shared__ __align__(16) float    sHf[ROWS * HFSTR];
    __shared__ int   sX[ROWS * XSTR];
    __shared__ float sLogit[ROWS][On];
    __shared__ float sMLS[ROWS];
    __shared__ float sPad[6200];   // 24.8KB pad: total ~81KB -> exactly 1 block/CU

    const int tid  = threadIdx.x;
    const int blk  = blockIdx.x;
    const int row0 = blk * ROWS;

    // volatile touch keeps sPad (and the 1-block/CU LDS footprint) alive
    ((volatile float*)sPad)[tid % 6200] = 0.0f;

    const int u    = tid >> 6;       // wave 0/1 -> owns h features [64u, 64u+64)
    const int lane = tid & 63;
    const int n    = lane & 15;      // batch col (B/C) AND A fragment row m
    const int q    = lane >> 4;      // quad
    const int k0   = 2 * u,     k1 = 2 * u + 1;   // own fragment indices
    const int o0   = 2 - 2 * u, o1 = 3 - 2 * u;   // other wave's fragment indices

    // ---- A operand (static, 80 VGPRs): 4 tiles/wave with PERMUTED row map
    //   F(tau, r) = 64u + 32*(tau>>1) + 8*(r>>2) + 4*(tau&1) + (r&3)
    // so C reg i of tile tau at lane (q,n) == h feature F(tau,4q+i). The packed
    // tanh output of tiles (0,1) is then EXACTLY own B-fragment k0 (and (2,3)
    // -> k1): zero cross-lane movement, own state never leaves VGPRs.
    // K order: k<128 W_hh col k; 128..147 W_ih; 148 fused bias (constant-1 xe
    // col). Pre-scaled by 2*log2e (tanh input fusion).
    half8 Ah[4][KC];
    #pragma unroll
    for (int tau = 0; tau < 4; ++tau) {
        const int f = 64 * u + 32 * (tau >> 1) + 8 * (n >> 2) + 4 * (tau & 1) + (n & 3);
        #pragma unroll
        for (int kc = 0; kc < 4; ++kc) {
            const float* p = &W_hh[f * Hn + kc * 32 + q * 8];
            #pragma unroll
            for (int i = 0; i < 8; ++i)
                Ah[tau][kc][i] = (_Float16)(p[i] * ASCALE);
        }
        #pragma unroll
        for (int i = 0; i < 8; ++i) {
            int e = q * 8 + i;
            float v = 0.0f;
            if (e < En)       v = W_ih[f * En + e];
            else if (e == 20) v = b_ih[f] + b_hh[f];
            Ah[tau][4][i] = (_Float16)(v * ASCALE);
        }
    }

    // ---- build embT (fp16) with constant-1 bias column (cols 0..31 used)
    for (int idx = tid; idx < Vn * 32; idx += NTHR) {
        int c = idx >> 5, j = idx & 31;
        float v = (j < En) ? emb[c * En + j] : (j == 20 ? 1.0f : 0.0f);
        sEmb[c * ESTR + j] = (_Float16)v;
    }
    // ---- stage vocab ids (int4-vectorized; 512 % 4 == 0 -> no row crossing)
    for (int idx = tid * 4; idx < ROWS * Tn; idx += NTHR * 4) {
        int4 v = *(const int4*)&x[row0 * Tn + idx];
        int r = idx >> 9, t = idx & 511;
        sX[r * XSTR + t]     = v.x;
        sX[r * XSTR + t + 1] = v.y;
        sX[r * XSTR + t + 2] = v.z;
        sX[r * XSTR + t + 3] = v.w;
    }
    // ---- zero both exchange buffers (h0 = 0)
    for (int idx = tid; idx < 2 * 4 * 64; idx += NTHR)
        ((uint4*)exB)[idx] = make_uint4(0u, 0u, 0u, 0u);
    __syncthreads();

    const int Lmax  = xlen[row0];        // sorted descending -> block trip count
    const int len_n = xlen[row0 + n];    // per batch-col freeze point

    // ---- xe pipeline: lane (q,n) needs xe cols 8q..8q+7 of token x[n][t+1];
    // the xe MFMA partial P[tau] for the NEXT step is accumulated pre-barrier.
    int     idN;
    floatx4 P[4];
    {
        int id0 = sX[n * XSTR];
        half8 xe0 = *(const half8*)&sEmb[id0 * ESTR + 8 * q];
        #pragma unroll
        for (int tau = 0; tau < 4; ++tau) {
            floatx4 z = {0.f, 0.f, 0.f, 0.f};
            P[tau] = __builtin_amdgcn_mfma_f32_16x16x32_f16(Ah[tau][4], xe0, z, 0, 0, 0);
        }
        idN = sX[n * XSTR + (Lmax > 1 ? 1 : 0)];
    }

    float hreg[16];
    #pragma unroll
    for (int i = 0; i < 16; ++i) hreg[i] = 0.f;

    // one step: post-barrier = {read 2 other-frags, 2-deep MFMA x4 tiles on top
    // of prebuilt P, tanh+freeze+pack}; pre-barrier (for t+1) = {write own frags,
    // xe read, 12 MFMAs: xe + own-frag contributions}. ONE 2-wave barrier.
    #define RNN_STEP(BR, BW, t)                                                     \
    {                                                                               \
        half8 bo0 = *(const half8*)&exB[BR][o0][lane];                              \
        half8 bo1 = *(const half8*)&exB[BR][o1][lane];                              \
        half8 xeN = *(const half8*)&sEmb[idN * ESTR + 8 * q];                       \
        int tn = (t) + 2;                                                           \
        int idN2 = sX[n * XSTR + (tn < Lmax ? tn : Lmax - 1)];                      \
        floatx4 a0 = __builtin_amdgcn_mfma_f32_16x16x32_f16(Ah[0][o0], bo0, P[0], 0,0,0); \
        floatx4 a1 = __builtin_amdgcn_mfma_f32_16x16x32_f16(Ah[1][o0], bo0, P[1], 0,0,0); \
        floatx4 a2 = __builtin_amdgcn_mfma_f32_16x16x32_f16(Ah[2][o0], bo0, P[2], 0,0,0); \
        floatx4 a3 = __builtin_amdgcn_mfma_f32_16x16x32_f16(Ah[3][o0], bo0, P[3], 0,0,0); \
        a0 = __builtin_amdgcn_mfma_f32_16x16x32_f16(Ah[0][o1], bo1, a0, 0, 0, 0);   \
        a1 = __builtin_amdgcn_mfma_f32_16x16x32_f16(Ah[1][o1], bo1, a1, 0, 0, 0);   \
        a2 = __builtin_amdgcn_mfma_f32_16x16x32_f16(Ah[2][o1], bo1, a2, 0, 0, 0);   \
        a3 = __builtin_amdgcn_mfma_f32_16x16x32_f16(Ah[3][o1], bo1, a3, 0, 0, 0);   \
        const bool upd = ((t) < len_n);                                             \
        _Pragma("unroll")                                                           \
        for (int i = 0; i < 4; ++i) {                                               \
            float v0 = tanh_scaled(a0[i]);                                          \
            float v1 = tanh_scaled(a1[i]);                                          \
            float v2 = tanh_scaled(a2[i]);                                          \
            float v3 = tanh_scaled(a3[i]);                                          \
            hreg[i]      = upd ? v0 : hreg[i];                                      \
            hreg[4 + i]  = upd ? v1 : hreg[4 + i];                                  \
            hreg[8 + i]  = upd ? v2 : hreg[8 + i];                                  \
            hreg[12 + i] = upd ? v3 : hreg[12 + i];                                 \
        }                                                                           \
        uint4 w0, w1;                                                               \
        w0.x = pk_u32(__builtin_amdgcn_cvt_pkrtz(hreg[0],  hreg[1]));               \
        w0.y = pk_u32(__builtin_amdgcn_cvt_pkrtz(hreg[2],  hreg[3]));               \
        w0.z = pk_u32(__builtin_amdgcn_cvt_pkrtz(hreg[4],  hreg[5]));               \
        w0.w = pk_u32(__builtin_amdgcn_cvt_pkrtz(hreg[6],  hreg[7]));               \
        w1.x = pk_u32(__builtin_amdgcn_cvt_pkrtz(hreg[8],  hreg[9]));               \
        w1.y = pk_u32(__builtin_amdgcn_cvt_pkrtz(hreg[10], hreg[11]));              \
        w1.z = pk_u32(__builtin_amdgcn_cvt_pkrtz(hreg[12], hreg[13]));              \
        w1.w = pk_u32(__builtin_amdgcn_cvt_pkrtz(hreg[14], hreg[15]));              \
        exB[BW][k0][lane] = w0;                                                     \
        exB[BW][k1][lane] = w1;                                                     \
        half8 own0 = as_half8(w0);                                                  \
        half8 own1 = as_half8(w1);                                                  \
        _Pragma("unroll")                                                           \
        for (int tau = 0; tau < 4; ++tau) {                                         \
            floatx4 z = {0.f, 0.f, 0.f, 0.f};                                       \
            P[tau] = __builtin_amdgcn_mfma_f32_16x16x32_f16(Ah[tau][4], xeN, z, 0,0,0); \
            P[tau] = __builtin_amdgcn_mfma_f32_16x16x32_f16(Ah[tau][k0], own0, P[tau], 0,0,0); \
            P[tau] = __builtin_amdgcn_mfma_f32_16x16x32_f16(Ah[tau][k1], own1, P[tau], 0,0,0); \
        }                                                                           \
        idN = idN2;                                                                 \
        __syncthreads();                                                            \
    }

    int t = 0;
    for (; t + 2 <= Lmax; t += 2) {
        RNN_STEP(0, 1, t);
        RNN_STEP(1, 0, t + 1);
    }
    if (t < Lmax) {
        RNN_STEP(0, 1, t);
    }
    #undef RNN_STEP

    // ---- publish final fp32 h: lane (q,n) of wave u holds
    // feature F(tau,4q+i) = 64u + 32*(tau>>1) + 4*(tau&1) + 8q + i, batch n.
    {
        float4 f0;
        f0.x = hreg[0];  f0.y = hreg[1];  f0.z = hreg[2];  f0.w = hreg[3];
        *(float4*)&sHf[n * HFSTR + 64 * u + 8 * q] = f0;
        f0.x = hreg[4];  f0.y = hreg[5];  f0.z = hreg[6];  f0.w = hreg[7];
        *(float4*)&sHf[n * HFSTR + 64 * u + 8 * q + 4] = f0;
        f0.x = hreg[8];  f0.y = hreg[9];  f0.z = hreg[10]; f0.w = hreg[11];
        *(float4*)&sHf[n * HFSTR + 64 * u + 32 + 8 * q] = f0;
        f0.x = hreg[12]; f0.y = hreg[13]; f0.z = hreg[14]; f0.w = hreg[15];
        *(float4*)&sHf[n * HFSTR + 64 * u + 32 + 8 * q + 4] = f0;
    }
    __syncthreads();

    // ---- epilogue: logits = relu(h) @ W_out^T + b_out, then log_softmax
    for (int it = tid; it < ROWS * On; it += NTHR) {
        int r = it / On, c = it % On;
        float acc = b_out[c];
        for (int k = 0; k < Hn; ++k) {
            float hv = sHf[r * HFSTR + k];
            hv = hv > 0.0f ? hv : 0.0f;
            acc = fmaf(hv, W_out[c * Hn + k], acc);
        }
        sLogit[r][c] = acc;
    }
    __syncthreads();

    if (tid < ROWS) {
        float m = -INFINITY;
        #pragma unroll
        for (int c = 0; c < On; ++c) m = fmaxf(m, sLogit[tid][c]);
        float s = 0.0f;
        #pragma unroll
        for (int c = 0; c < On; ++c) s += __expf(sLogit[tid][c] - m);
        sMLS[tid] = m + __logf(s);
    }
    __syncthreads();

    for (int it = tid; it < ROWS * On; it += NTHR) {
        int r = it / On, c = it % On;
        out[(row0 + r) * On + c] = sLogit[r][c] - sMLS[r];
    }
}

extern "C" void kernel_launch(void* const* d_in, const int* in_sizes, int n_in,
                              void* d_out, int out_size, void* d_ws, size_t ws_size,
                              hipStream_t stream) {
    const int*   x     = (const int*)d_in[0];
    const int*   xlen  = (const int*)d_in[1];
    const float* emb   = (const float*)d_in[2];
    const float* W_ih  = (const float*)d_in[3];
    const float* W_hh  = (const float*)d_in[4];
    const float* b_ih  = (const float*)d_in[5];
    const float* b_hh  = (const float*)d_in[6];
    const float* W_out = (const float*)d_in[7];
    const float* b_out = (const float*)d_in[8];
    float*       out   = (float*)d_out;

    rnn_mfma_kernel<<<NBLK, NTHR, 0, stream>>>(x, xlen, emb, W_ih, W_hh,
                                               b_ih, b_hh, W_out, b_out, out);
}

// Round 5
// 249.420 us; speedup vs baseline: 2.6556x; 2.6556x over previous
//
#include <hip/hip_runtime.h>
#include <math.h>

#define Bn 4096
#define Tn 512
#define Vn 57
#define En 20
#define Hn 128
#define On 18
#define ROWS 16          // batch rows per block (= MFMA N)
#define NTHR 512         // 8 waves = 2/SIMD: proven latency-hiding topology (R2)
#define NBLK (Bn / ROWS) // 256 blocks -> 1 per CU (LDS pad keeps it that way)
#define XWSTR 132        // xw table row stride (floats): rows 16B-aligned, bank=(4id+f)%32
#define XBSTR 516        // id byte-row stride: word bank = (n + t/4) % 32, conflict-free
#define HFSTR 132        // final-h fp32 row stride
#define ASCALE 2.8853900817779268f   // 2*log2(e): folds tanh's 2x and log2e mul in

typedef _Float16 half8  __attribute__((ext_vector_type(8)));
typedef __fp16   fp16x2 __attribute__((ext_vector_type(2)));   // cvt_pkrtz native type
typedef float    floatx4 __attribute__((ext_vector_type(4)));

// acc is pre-scaled by 2*log2e: tanh(x) = 1 - 2/(1+2^(2x*log2e))
__device__ __forceinline__ float tanh_scaled(float z) {
    float e = __builtin_amdgcn_exp2f(z);          // v_exp_f32
    float r = __builtin_amdgcn_rcpf(e + 1.0f);    // v_rcp_f32
    return fmaf(-2.0f, r, 1.0f);
}

__device__ __forceinline__ unsigned pk_u32(fp16x2 v) {
    union { fp16x2 h; unsigned u; } c; c.h = v; return c.u;
}

__device__ __forceinline__ half8 as_half8(uint4 v) {
    union { uint4 u; half8 h; } c; c.u = v; return c.h;
}

// (512, 2): 8 waves = 2/EU -> VGPR cap 256; demand ~75 -> no spill (R4 lesson:
// keep per-wave A footprint at 16 VGPRs).
__launch_bounds__(NTHR, 2)
__global__ void rnn_mfma_kernel(const int* __restrict__ x,
                                const int* __restrict__ xlen,
                                const float* __restrict__ emb,
                                const float* __restrict__ W_ih,
                                const float* __restrict__ W_hh,
                                const float* __restrict__ b_ih,
                                const float* __restrict__ b_hh,
                                const float* __restrict__ W_out,
                                const float* __restrict__ b_out,
                                float* __restrict__ out)
{
    // Exchange buffers: h-fragment kc for lane l at exB[buf][kc][l] (uint4=half8,
    // k = 32kc+8q+j, batch col n = l&15). Each wave writes one uint2 (its 16
    // features land in-place via the A-row permutation) and KEEPS it in regs;
    // per step it reads 3 full foreign frags + only the 8B sibling half of its
    // own frag. Double-buffered: ONE barrier per step.
    __shared__ __align__(16) uint4 exB[2][4][64];
    __shared__ __align__(16) float sXW[Vn * XWSTR];   // xw[id][f] = (W_ih.emb[id]+b)*ASCALE, f32
    __shared__ __align__(16) float sHf[ROWS * HFSTR];
    __shared__ __align__(16) unsigned char sXb[ROWS * XBSTR];  // token ids as bytes
    __shared__ float sLogit[ROWS][On];
    __shared__ float sMLS[ROWS];
    __shared__ float sPad[6500];   // 26KB pad: total ~80.3KB -> exactly 1 block/CU

    const int tid  = threadIdx.x;
    const int blk  = blockIdx.x;
    const int row0 = blk * ROWS;

    // volatile touch keeps sPad (and the 1-block/CU LDS footprint) alive
    ((volatile float*)sPad)[tid % 6500] = 0.0f;

    const int w    = tid >> 6;       // wave 0..7 -> owns 16 h features
    const int lane = tid & 63;
    const int n    = lane & 15;      // batch col (B/C) AND A fragment row m
    const int q    = lane >> 4;      // quad
    const int kcW  = w >> 1;         // which 32-k fragment this wave's output feeds
    const int bsel = w & 1;          // which uint2 half of the 16B frag slot

    // ---- A operand (static, 16 VGPRs), LOCAL fragment order: Ah[j] pairs with
    // global k-chunk kc=(kcW+j)&3, so j=0 is the frag containing OUR output —
    // registers statically indexed (no spill), addresses runtime-uniform.
    // PERMUTED row map: C output reg i of lane (q,n) == h feature
    // F = 32*kcW + 8q + 4*bsel + i, so the packed tanh output (uint2) is
    // EXACTLY the right 8B of B-fragment kcW. Pre-scaled by 2*log2e.
    half8 Ah[4];
    const int f = 32 * kcW + 8 * (n >> 2) + 4 * bsel + (n & 3);
    #pragma unroll
    for (int j = 0; j < 4; ++j) {
        const int kc = (kcW + j) & 3;
        const float* p = &W_hh[f * Hn + kc * 32 + q * 8];
        #pragma unroll
        for (int i = 0; i < 8; ++i)
            Ah[j][i] = (_Float16)(p[i] * ASCALE);
    }

    // ---- xw lookup table (f32, exact): kills the per-step xe MFMA + gather.
    // xw[v][f] = (b_ih[f] + b_hh[f] + sum_e emb[v][e]*W_ih[f][e]) * ASCALE
    for (int idx = tid; idx < Vn * Hn; idx += NTHR) {
        int vo = idx >> 7, ff = idx & 127;
        float acc = b_ih[ff] + b_hh[ff];
        #pragma unroll
        for (int e = 0; e < En; ++e)
            acc = fmaf(emb[vo * En + e], W_ih[ff * En + e], acc);
        sXW[vo * XWSTR + ff] = acc * ASCALE;
    }
    // ---- stage vocab ids as bytes (vocab=57 < 256); int4 load, uchar4 store
    for (int idx = tid * 4; idx < ROWS * Tn; idx += NTHR * 4) {
        int4 v = *(const int4*)&x[row0 * Tn + idx];
        int r = idx >> 9, t = idx & 511;
        uchar4 bb;
        bb.x = (unsigned char)v.x; bb.y = (unsigned char)v.y;
        bb.z = (unsigned char)v.z; bb.w = (unsigned char)v.w;
        *(uchar4*)&sXb[r * XBSTR + t] = bb;
    }
    // ---- zero both exchange buffers (h0 = 0)
    for (int idx = tid; idx < 2 * 4 * 64; idx += NTHR)
        ((uint4*)exB)[idx] = make_uint4(0u, 0u, 0u, 0u);
    __syncthreads();

    const int Lmax  = xlen[row0];        // sorted descending -> block trip count
    const int len_n = xlen[row0 + n];    // per batch-col freeze point
    const int wOffH = 32 * kcW + 8 * q + 4 * bsel;   // this lane's feature base

    // ---- xw pipeline: lane (q,n) needs xw[id(t)][wOffH..+3] (f32x4) as its
    // accumulator init. Prefetched one step ahead (pre-barrier read).
    int    idN;
    float4 XWc;
    {
        int id0 = sXb[n * XBSTR];
        XWc = *(const float4*)&sXW[id0 * XWSTR + wOffH];
        idN = sXb[n * XBSTR + (Lmax > 1 ? 1 : 0)];
    }
    uint2 own = make_uint2(0u, 0u);      // our 8B of frag kcW (h = 0)
    float hreg[4] = {0.f, 0.f, 0.f, 0.f};

    const int j1 = (kcW + 1) & 3, j2 = (kcW + 2) & 3, j3 = (kcW + 3) & 3;

    // one step: sib b64 + 3 frag b128 reads, prefetch xw/id for t+1, 4 MFMA
    // (aE: xw-init + own-frag + j2, depth 2; aO: j1 + j3, depth 2), tanh+freeze
    // +pack, one uint2 publish (kept in regs), ONE barrier. Unrolled by 2.
    #define RNN_STEP(BR, BW, t)                                                   \
    {                                                                             \
        uint2 sib = *(const uint2*)((const _Float16*)&exB[BR][kcW][0]             \
                                    + lane * 8 + 4 * (1 - bsel));                 \
        half8 bf1 = *(const half8*)&exB[BR][j1][lane];                            \
        half8 bf2 = *(const half8*)&exB[BR][j2][lane];                            \
        half8 bf3 = *(const half8*)&exB[BR][j3][lane];                            \
        float4 XWn = *(const float4*)&sXW[idN * XWSTR + wOffH];                   \
        int tn = (t) + 2;                                                         \
        int idN2 = sXb[n * XBSTR + (tn < Lmax ? tn : Lmax - 1)];                  \
        uint4 ko;                                                                 \
        ko.x = bsel ? sib.x : own.x;  ko.y = bsel ? sib.y : own.y;                \
        ko.z = bsel ? own.x : sib.x;  ko.w = bsel ? own.y : sib.y;                \
        half8 bf0 = as_half8(ko);                                                 \
        floatx4 aE = {XWc.x, XWc.y, XWc.z, XWc.w};                                \
        floatx4 aO = {0.f, 0.f, 0.f, 0.f};                                        \
        aE = __builtin_amdgcn_mfma_f32_16x16x32_f16(Ah[0], bf0, aE, 0, 0, 0);     \
        aO = __builtin_amdgcn_mfma_f32_16x16x32_f16(Ah[1], bf1, aO, 0, 0, 0);     \
        aE = __builtin_amdgcn_mfma_f32_16x16x32_f16(Ah[2], bf2, aE, 0, 0, 0);     \
        aO = __builtin_amdgcn_mfma_f32_16x16x32_f16(Ah[3], bf3, aO, 0, 0, 0);     \
        const bool upd = ((t) < len_n);                                           \
        _Pragma("unroll")                                                         \
        for (int i = 0; i < 4; ++i) {                                             \
            float v = tanh_scaled(aE[i] + aO[i]);                                 \
            hreg[i] = upd ? v : hreg[i];                                          \
        }                                                                         \
        uint2 pk;                                                                 \
        pk.x = pk_u32(__builtin_amdgcn_cvt_pkrtz(hreg[0], hreg[1]));              \
        pk.y = pk_u32(__builtin_amdgcn_cvt_pkrtz(hreg[2], hreg[3]));              \
        *(uint2*)((_Float16*)&exB[BW][kcW][0] + lane * 8 + 4 * bsel) = pk;        \
        own = pk;                                                                 \
        XWc = XWn; idN = idN2;                                                    \
        __syncthreads();                                                          \
    }

    int t = 0;
    for (; t + 2 <= Lmax; t += 2) {
        RNN_STEP(0, 1, t);
        RNN_STEP(1, 0, t + 1);
    }
    if (t < Lmax) {
        RNN_STEP(0, 1, t);
    }
    #undef RNN_STEP

    // ---- publish final fp32 h: lane (q,n) of wave w holds features wOffH+0..3
    {
        float4 f0;
        f0.x = hreg[0]; f0.y = hreg[1]; f0.z = hreg[2]; f0.w = hreg[3];
        *(float4*)&sHf[n * HFSTR + wOffH] = f0;
    }
    __syncthreads();

    // ---- epilogue: logits = relu(h) @ W_out^T + b_out, then log_softmax
    for (int it = tid; it < ROWS * On; it += NTHR) {
        int r = it / On, c = it % On;
        float acc = b_out[c];
        for (int k = 0; k < Hn; ++k) {
            float hv = sHf[r * HFSTR + k];
            hv = hv > 0.0f ? hv : 0.0f;
            acc = fmaf(hv, W_out[c * Hn + k], acc);
        }
        sLogit[r][c] = acc;
    }
    __syncthreads();

    if (tid < ROWS) {
        float m = -INFINITY;
        #pragma unroll
        for (int c = 0; c < On; ++c) m = fmaxf(m, sLogit[tid][c]);
        float s = 0.0f;
        #pragma unroll
        for (int c = 0; c < On; ++c) s += __expf(sLogit[tid][c] - m);
        sMLS[tid] = m + __logf(s);
    }
    __syncthreads();

    for (int it = tid; it < ROWS * On; it += NTHR) {
        int r = it / On, c = it % On;
        out[(row0 + r) * On + c] = sLogit[r][c] - sMLS[r];
    }
}

extern "C" void kernel_launch(void* const* d_in, const int* in_sizes, int n_in,
                              void* d_out, int out_size, void* d_ws, size_t ws_size,
                              hipStream_t stream) {
    const int*   x     = (const int*)d_in[0];
    const int*   xlen  = (const int*)d_in[1];
    const float* emb   = (const float*)d_in[2];
    const float* W_ih  = (const float*)d_in[3];
    const float* W_hh  = (const float*)d_in[4];
    const float* b_ih  = (const float*)d_in[5];
    const float* b_hh  = (const float*)d_in[6];
    const float* W_out = (const float*)d_in[7];
    const float* b_out = (const float*)d_in[8];
    float*       out   = (float*)d_out;

    rnn_mfma_kernel<<<NBLK, NTHR, 0, stream>>>(x, xlen, emb, W_ih, W_hh,
                                               b_ih, b_hh, W_out, b_out, out);
}

// Round 6
// 242.779 us; speedup vs baseline: 2.7283x; 1.0274x over previous
//
#include <hip/hip_runtime.h>
#include <math.h>

#define Bn 4096
#define Tn 512
#define Vn 57
#define En 20
#define Hn 128
#define On 18
#define ROWS 16          // batch rows per block (= MFMA N)
#define NTHR 512         // 8 waves = 2/SIMD: proven latency-hiding topology (R2)
#define NBLK (Bn / ROWS) // 256 blocks -> 1 per CU (LDS pad keeps it that way)
#define XWSTR 132        // xw table row stride (floats), 16B-aligned rows
#define XBSTR 516        // id byte-row stride: word bank = (n + t/4) % 32, conflict-free
#define HFSTR 132        // final-h fp32 row stride
#define ASCALE 2.8853900817779268f   // 2*log2(e): folds tanh's 2x and log2e mul in

typedef _Float16 half8  __attribute__((ext_vector_type(8)));
typedef __fp16   fp16x2 __attribute__((ext_vector_type(2)));   // cvt_pkrtz native type
typedef float    floatx4 __attribute__((ext_vector_type(4)));

// acc is pre-scaled by 2*log2e: tanh(x) = 1 - 2/(1+2^(2x*log2e))
__device__ __forceinline__ float tanh_scaled(float z) {
    float e = __builtin_amdgcn_exp2f(z);          // v_exp_f32
    float r = __builtin_amdgcn_rcpf(e + 1.0f);    // v_rcp_f32
    return fmaf(-2.0f, r, 1.0f);
}

__device__ __forceinline__ unsigned pk_u32(fp16x2 v) {
    union { fp16x2 h; unsigned u; } c; c.h = v; return c.u;
}

// (512, 2): 8 waves = 2/EU -> VGPR cap 256; demand ~80 -> no spill.
__launch_bounds__(NTHR, 2)
__global__ void rnn_mfma_kernel(const int* __restrict__ x,
                                const int* __restrict__ xlen,
                                const float* __restrict__ emb,
                                const float* __restrict__ W_ih,
                                const float* __restrict__ W_hh,
                                const float* __restrict__ b_ih,
                                const float* __restrict__ b_hh,
                                const float* __restrict__ W_out,
                                const float* __restrict__ b_out,
                                float* __restrict__ out)
{
    // Exchange buffers: h-fragment kc for lane l at exB[buf][kc][l] (uint4=half8,
    // k = 32kc+8q+j, batch col n = l&15). Each wave writes one uint2 (its 16
    // features land in-place via the A-row permutation); every wave reads all 4
    // frags as uniform b128 (stride-16B, conflict-free). Double-buffered:
    // ONE barrier per step.
    __shared__ __align__(16) uint4 exB[2][4][64];
    __shared__ __align__(16) float sXW[Vn * XWSTR];   // xw[id][f] = (W_ih.emb[id]+b)*ASCALE, f32
    __shared__ __align__(16) float sHf[ROWS * HFSTR];
    __shared__ __align__(16) unsigned char sXb[ROWS * XBSTR];  // token ids as bytes
    __shared__ float sLogit[ROWS][On];
    __shared__ float sMLS[ROWS];
    __shared__ float sPad[6200];   // 24.8KB pad: total ~81KB -> exactly 1 block/CU

    const int tid  = threadIdx.x;
    const int blk  = blockIdx.x;
    const int row0 = blk * ROWS;

    // volatile touch keeps sPad (and the 1-block/CU LDS footprint) alive
    ((volatile float*)sPad)[tid % 6200] = 0.0f;

    const int w    = tid >> 6;       // wave 0..7 -> owns 16 h features
    const int lane = tid & 63;
    const int n    = lane & 15;      // batch col (B/C) AND A fragment row m
    const int q    = lane >> 4;      // quad
    const int kcW  = w >> 1;         // which 32-k fragment this wave's output feeds
    const int bsel = w & 1;          // which uint2 half of the 16B frag slot

    // ---- A operand (static, 16 VGPRs): PERMUTED row map so C output reg i of
    // lane (q,n) == h feature F = 32*kcW + 8q + 4*bsel + i; the packed tanh
    // output (uint2) is EXACTLY the right 8B of B-fragment kcW -- no cross-lane
    // movement, one ds_write_b64 per lane per step.
    //   A row m = lane&15 loads weight row F(m) = 32*kcW + 8*(m>>2) + 4*bsel + (m&3).
    // K order: k = kc*32 .. (W_hh columns only; input projection now comes from
    // the f32 XW table as accumulator init). Pre-scaled by 2*log2e.
    half8 Ah[4];
    const int f = 32 * kcW + 8 * (n >> 2) + 4 * bsel + (n & 3);
    #pragma unroll
    for (int kc = 0; kc < 4; ++kc) {
        const float* p = &W_hh[f * Hn + kc * 32 + q * 8];
        #pragma unroll
        for (int i = 0; i < 8; ++i)
            Ah[kc][i] = (_Float16)(p[i] * ASCALE);
    }

    // ---- xw lookup table (f32, exact): kills the per-step xe MFMA + fp16 round
    // of the input projection. xw[v][f] = (b_ih+b_hh+emb[v].W_ih[f,:]) * ASCALE
    for (int idx = tid; idx < Vn * Hn; idx += NTHR) {
        int vo = idx >> 7, ff = idx & 127;
        float acc = b_ih[ff] + b_hh[ff];
        #pragma unroll
        for (int e = 0; e < En; ++e)
            acc = fmaf(emb[vo * En + e], W_ih[ff * En + e], acc);
        sXW[vo * XWSTR + ff] = acc * ASCALE;
    }
    // ---- stage vocab ids as bytes (vocab=57 < 256); int4 load, uchar4 store
    for (int idx = tid * 4; idx < ROWS * Tn; idx += NTHR * 4) {
        int4 v = *(const int4*)&x[row0 * Tn + idx];
        int r = idx >> 9, t = idx & 511;
        uchar4 bb;
        bb.x = (unsigned char)v.x; bb.y = (unsigned char)v.y;
        bb.z = (unsigned char)v.z; bb.w = (unsigned char)v.w;
        *(uchar4*)&sXb[r * XBSTR + t] = bb;
    }
    // ---- zero both exchange buffers (h0 = 0)
    for (int idx = tid; idx < 2 * 4 * 64; idx += NTHR)
        ((uint4*)exB)[idx] = make_uint4(0u, 0u, 0u, 0u);
    __syncthreads();

    const int Lmax  = xlen[row0];        // sorted descending -> block trip count
    const int len_n = xlen[row0 + n];    // per batch-col freeze point
    const int wOffH = 32 * kcW + 8 * q + 4 * bsel;   // this lane's feature base

    // ---- xw pipeline: lane (q,n) needs xw[id(t)][wOffH..+3] (f32x4) as its
    // accumulator-0 init. Prefetched one step ahead (read issued in step t-1).
    int    idN;
    float4 XWc;
    {
        int id0 = sXb[n * XBSTR];
        XWc = *(const float4*)&sXW[id0 * XWSTR + wOffH];
        idN = sXb[n * XBSTR + (Lmax > 1 ? 1 : 0)];
    }
    float hreg[4] = {0.f, 0.f, 0.f, 0.f};

    // one step: 4 uniform b128 frag reads (streaming), prefetch xw/id for t+1,
    // 4 INDEPENDENT depth-1 MFMAs (a0 init = f32 xw, a1..3 = 0) pipelined
    // against the frag returns, 2-deep add tree, tanh+freeze+pack, one uint2
    // publish, ONE barrier. Buffers compile-time (t unrolled by 2).
    #define RNN_STEP(BR, BW, t)                                                   \
    {                                                                             \
        half8 bf0 = *(const half8*)&exB[BR][0][lane];                             \
        half8 bf1 = *(const half8*)&exB[BR][1][lane];                             \
        half8 bf2 = *(const half8*)&exB[BR][2][lane];                             \
        half8 bf3 = *(const half8*)&exB[BR][3][lane];                             \
        float4 XWn = *(const float4*)&sXW[idN * XWSTR + wOffH];                   \
        int tn = (t) + 2;                                                         \
        int idN2 = sXb[n * XBSTR + (tn < Lmax ? tn : Lmax - 1)];                  \
        floatx4 a0 = {XWc.x, XWc.y, XWc.z, XWc.w};                                \
        floatx4 a1 = {0.f, 0.f, 0.f, 0.f};                                        \
        floatx4 a2 = {0.f, 0.f, 0.f, 0.f};                                        \
        floatx4 a3 = {0.f, 0.f, 0.f, 0.f};                                        \
        a0 = __builtin_amdgcn_mfma_f32_16x16x32_f16(Ah[0], bf0, a0, 0, 0, 0);     \
        a1 = __builtin_amdgcn_mfma_f32_16x16x32_f16(Ah[1], bf1, a1, 0, 0, 0);     \
        a2 = __builtin_amdgcn_mfma_f32_16x16x32_f16(Ah[2], bf2, a2, 0, 0, 0);     \
        a3 = __builtin_amdgcn_mfma_f32_16x16x32_f16(Ah[3], bf3, a3, 0, 0, 0);     \
        const bool upd = ((t) < len_n);                                           \
        _Pragma("unroll")                                                         \
        for (int i = 0; i < 4; ++i) {                                             \
            float v = tanh_scaled((a0[i] + a1[i]) + (a2[i] + a3[i]));             \
            hreg[i] = upd ? v : hreg[i];                                          \
        }                                                                         \
        uint2 pk;                                                                 \
        pk.x = pk_u32(__builtin_amdgcn_cvt_pkrtz(hreg[0], hreg[1]));              \
        pk.y = pk_u32(__builtin_amdgcn_cvt_pkrtz(hreg[2], hreg[3]));              \
        *(uint2*)((_Float16*)&exB[BW][kcW][0] + lane * 8 + 4 * bsel) = pk;        \
        XWc = XWn; idN = idN2;                                                    \
        __syncthreads();                                                          \
    }

    int t = 0;
    for (; t + 2 <= Lmax; t += 2) {
        RNN_STEP(0, 1, t);
        RNN_STEP(1, 0, t + 1);
    }
    if (t < Lmax) {
        RNN_STEP(0, 1, t);
    }
    #undef RNN_STEP

    // ---- publish final fp32 h: lane (q,n) of wave w holds features wOffH+0..3
    {
        float4 f0;
        f0.x = hreg[0]; f0.y = hreg[1]; f0.z = hreg[2]; f0.w = hreg[3];
        *(float4*)&sHf[n * HFSTR + wOffH] = f0;
    }
    __syncthreads();

    // ---- epilogue: logits = relu(h) @ W_out^T + b_out, then log_softmax
    for (int it = tid; it < ROWS * On; it += NTHR) {
        int r = it / On, c = it % On;
        float acc = b_out[c];
        for (int k = 0; k < Hn; ++k) {
            float hv = sHf[r * HFSTR + k];
            hv = hv > 0.0f ? hv : 0.0f;
            acc = fmaf(hv, W_out[c * Hn + k], acc);
        }
        sLogit[r][c] = acc;
    }
    __syncthreads();

    if (tid < ROWS) {
        float m = -INFINITY;
        #pragma unroll
        for (int c = 0; c < On; ++c) m = fmaxf(m, sLogit[tid][c]);
        float s = 0.0f;
        #pragma unroll
        for (int c = 0; c < On; ++c) s += __expf(sLogit[tid][c] - m);
        sMLS[tid] = m + __logf(s);
    }
    __syncthreads();

    for (int it = tid; it < ROWS * On; it += NTHR) {
        int r = it / On, c = it % On;
        out[(row0 + r) * On + c] = sLogit[r][c] - sMLS[r];
    }
}

extern "C" void kernel_launch(void* const* d_in, const int* in_sizes, int n_in,
                              void* d_out, int out_size, void* d_ws, size_t ws_size,
                              hipStream_t stream) {
    const int*   x     = (const int*)d_in[0];
    const int*   xlen  = (const int*)d_in[1];
    const float* emb   = (const float*)d_in[2];
    const float* W_ih  = (const float*)d_in[3];
    const float* W_hh  = (const float*)d_in[4];
    const float* b_ih  = (const float*)d_in[5];
    const float* b_hh  = (const float*)d_in[6];
    const float* W_out = (const float*)d_in[7];
    const float* b_out = (const float*)d_in[8];
    float*       out   = (float*)d_out;

    rnn_mfma_kernel<<<NBLK, NTHR, 0, stream>>>(x, xlen, emb, W_ih, W_hh,
                                               b_ih, b_hh, W_out, b_out, out);
}